// Round 17
// baseline (139.886 us; speedup 1.0000x reference)
//
#include <hip/hip_runtime.h>
#include <stdint.h>

#define NBATCH 32
#define VPT    4
#define BPTS   1024            // points per pass1 block (256*VPT)
#define BPTS_SHIFT 10
#define CAP_BLK 256            // candidate slots per block (expected ~82)
#define MSTRIDE 72             // u32s per block meta row: cnt[32] clo[32] candcnt pad[7]
#define CAPTOT 6144            // LDS gather capacity (expected ~2500/segment)
#define CAP2   512             // sub-bucket capacity in rank select
#define APPLY_BLOCKS 2048      // grid-stride apply (G11)

typedef unsigned long long u64;
typedef unsigned int u32;
typedef float f4 __attribute__((ext_vector_type(4)));

struct WsHdr {
  u64 keysel[NBATCH];   // k-th smallest 56-bit key per segment (b-byte masked off)
  int counts[NBATCH];   // fallback path only
};
// ws: WsHdr | u32 meta[nblk*MSTRIDE] | u64 cand[nblk*CAP_BLK]
// Nothing pre-zeroed: every meta row is fully written by its owning block;
// cand slots are only read up to the stored (clamped) count.

__device__ __forceinline__ u32 ordbits(float s) {
  u32 u = __float_as_uint(s);
  return (u & 0x80000000u) ? ~u : (u | 0x80000000u);
}
__device__ __forceinline__ u32 obL() { return ordbits(0.46f); }
__device__ __forceinline__ u32 obR() { return ordbits(0.54f); }

// ---------------- fast path (3 kernels, no zeroing, no global atomics) ------------

__global__ void k_pass1(const int* __restrict__ batch, const float* __restrict__ scores,
                        int n, u32* __restrict__ meta, u64* __restrict__ cand) {
  __shared__ int hc[NBATCH], hl[NBATCH];
  __shared__ int sc[256];
  int t = threadIdx.x, blk = blockIdx.x;
  if (t < NBATCH) { hc[t] = 0; hl[t] = 0; }
  __syncthreads();

  u64 wk[VPT]; int wcnt = 0;
  int i0 = blk * BPTS + t * VPT;
  #pragma unroll
  for (int v = 0; v < VPT; ++v) {
    int i = i0 + v;
    if (i < n) {
      int b = batch[i];
      u32 ob = ordbits(scores[i]);
      bool lo = ob < obL();
      u64 act = __ballot(1);
      int lead = (int)__ffsll((long long)act) - 1;
      int b0 = __shfl(b, lead, 64);
      bool uni = (__ballot(b == b0) == act);
      if (uni) {
        u64 lom = __ballot(lo);
        if ((t & 63) == lead) {
          atomicAdd(&hc[b0], (int)__popcll(act));
          if (lom) atomicAdd(&hl[b0], (int)__popcll(lom));
        }
      } else {
        atomicAdd(&hc[b], 1);
        if (lo) atomicAdd(&hl[b], 1);
      }
      if (!lo && ob < obR())
        wk[wcnt++] = ((u64)(u32)b << 56) | ((u64)ob << 24) | (u32)i;
    }
  }
  // block-wide compaction of window candidates (LDS scan, deterministic)
  sc[t] = wcnt; __syncthreads();
  for (int off = 1; off < 256; off <<= 1) {
    int v = (t >= off) ? sc[t - off] : 0;
    __syncthreads(); sc[t] += v; __syncthreads();
  }
  int excl = sc[t] - wcnt;
  int m = sc[255];
  u64* dst = cand + (size_t)blk * CAP_BLK;
  for (int j = 0; j < wcnt; ++j)
    if (excl + j < CAP_BLK) dst[excl + j] = wk[j];
  __syncthreads();
  u32* mrow = meta + (size_t)blk * MSTRIDE;
  if (t < NBATCH) { mrow[t] = (u32)hc[t]; mrow[NBATCH + t] = (u32)hl[t]; }
  if (t == 0) mrow[64] = (u32)m;              // true count (may exceed CAP_BLK)
}

// k_final: r13 form (coalesced meta reduce + range-limited gather)
__global__ void k_final(const float* __restrict__ scores, const u32* __restrict__ meta,
                        int nblk, const u64* __restrict__ cand, WsHdr* ws) {
  __shared__ u64 ck[CAPTOT];     // 48KB
  __shared__ u64 ck2[CAP2];      // 4KB
  __shared__ int sc[256];
  __shared__ int cw[NBATCH], clw[NBATCH], stw[NBATCH];
  __shared__ int sh_w, sh_krem, sh_m, sh_m2, sh_bad;
  int b = blockIdx.x, t = threadIdx.x;

  // Phase A: coalesced reduce of all 32 segment counts + clo + overflow flag.
  {
    int seg = t & 31, grp = t >> 5;
    int c = 0, l = 0, bd = 0;
    for (int blk = grp; blk < nblk; blk += 8) {
      const u32* mrow = meta + (size_t)blk * MSTRIDE;
      c += (int)mrow[seg];
      l += (int)mrow[NBATCH + seg];
      if (seg == 0) bd |= (mrow[64] > CAP_BLK);
    }
    sc[t] = c; __syncthreads();
    if (t < NBATCH) { int tot = 0; for (int g = 0; g < 8; ++g) tot += sc[g * 32 + t]; cw[t] = tot; }
    __syncthreads();
    sc[t] = l; __syncthreads();
    if (t < NBATCH) { int tot = 0; for (int g = 0; g < 8; ++g) tot += sc[g * 32 + t]; clw[t] = tot; }
    __syncthreads();
    sc[t] = bd; __syncthreads();
    if (t == 0) {
      int anyb = 0; for (int g = 0; g < 8; ++g) anyb |= sc[g * 32];
      sh_bad = anyb; sh_m = 0; sh_m2 = 0;
      int acc = 0;
      for (int x = 0; x < NBATCH; ++x) { stw[x] = acc; acc += cw[x]; }
    }
    __syncthreads();
  }
  int cnt = cw[b];
  if (cnt == 0) { if (t == 0) ws->keysel[b] = 0ull; return; }
  int krem = cnt >> 1;                        // ndrop = floor(cnt*0.5) exact
  int start = stw[b];

  // Phase B: gather candidates from ONLY this segment's block range (~32 blocks)
  {
    int blk0 = start >> BPTS_SHIFT;
    int blk1 = (start + cnt - 1) >> BPTS_SHIFT;
    int wave = t >> 6, lane = t & 63;
    for (int blk = blk0 + wave; blk <= blk1; blk += 4) {
      int cc = (int)meta[(size_t)blk * MSTRIDE + 64]; if (cc > CAP_BLK) cc = CAP_BLK;
      const u64* src = cand + (size_t)blk * CAP_BLK;
      for (int j = lane; j < cc; j += 64) {
        u64 s = src[j];
        if ((int)(s >> 56) == b) {
          int p = atomicAdd(&sh_m, 1);
          if (p < CAPTOT) ck[p] = s;
        }
      }
    }
  }
  __syncthreads();
  int m = sh_m;
  int krem2 = krem - clw[b];
  bool fast = !sh_bad && m <= CAPTOT && krem2 >= 0 && krem2 < m;

  if (fast) {
    const u32 span = obR() - obL();
    sc[t] = 0; __syncthreads();
    for (int j = t; j < m; j += 256) {
      u32 ob = (u32)(ck[j] >> 24);
      u32 bk = (u32)(((u64)(ob - obL()) << 8) / span);
      atomicAdd(&sc[bk], 1);
    }
    __syncthreads();
    int own = sc[t];
    for (int off = 1; off < 256; off <<= 1) {     // Hillis-Steele inclusive scan
      int v = (t >= off) ? sc[t - off] : 0;
      __syncthreads(); sc[t] += v; __syncthreads();
    }
    int excl = sc[t] - own;
    if (krem2 >= excl && krem2 < excl + own) { sh_w = t; sh_krem = krem2 - excl; }
    __syncthreads();
    int W = sh_w, krem3 = sh_krem;
    for (int j = t; j < m; j += 256) {            // compact winning bucket
      u32 ob = (u32)(ck[j] >> 24);
      u32 bk = (u32)(((u64)(ob - obL()) << 8) / span);
      if ((int)bk == W) {
        int p = atomicAdd(&sh_m2, 1);
        if (p < CAP2) ck2[p] = ck[j];
      }
    }
    __syncthreads();
    int m2 = sh_m2;
    if (m2 <= CAP2) {
      for (int j = t; j < m2; j += 256) {
        u64 key = ck2[j];
        int r = 0;
        for (int q = 0; q < m2; ++q) r += (ck2[q] < key);   // keys distinct
        if (r == krem3) ws->keysel[b] = key & 0x00FFFFFFFFFFFFFFull;  // strip b byte
      }
      return;
    }
    __syncthreads();   // sub-bucket overflow -> exact radix below
  }

  // exact in-block 8-bit radix select over segment [start, start+cnt)
  u64 prefix = 0; int kr = krem;
  for (int shift = 48; shift >= 0; shift -= 8) {
    sc[t] = 0;
    __syncthreads();
    for (int idx = t; idx < cnt; idx += 256) {
      u64 key = ((u64)ordbits(scores[start + idx]) << 24) | (u32)(start + idx);
      if ((key >> (shift + 8)) == prefix) atomicAdd(&sc[(int)((key >> shift) & 255)], 1);
    }
    __syncthreads();
    int own = sc[t];
    for (int off = 1; off < 256; off <<= 1) {
      int v = (t >= off) ? sc[t - off] : 0;
      __syncthreads(); sc[t] += v; __syncthreads();
    }
    int excl = sc[t] - own;
    if (kr >= excl && kr < excl + own) { sh_w = t; sh_krem = kr - excl; }
    __syncthreads();
    prefix = (prefix << 8) | (u32)sh_w;
    kr = sh_krem;
    __syncthreads();
  }
  if (t == 0) ws->keysel[b] = prefix;
}

// ---------------- apply: unroll x4, PLAIN loads + PLAIN stores (A/B load hint) ----
__global__ void k_apply(const f4* __restrict__ feats4,
                        const int* __restrict__ batch,
                        const float* __restrict__ scores,
                        const WsHdr* __restrict__ ws,
                        f4* __restrict__ out4, int n) {
  int t = threadIdx.x;
  int pl = t >> 4, ch = t & 15;
  int rstride = gridDim.x * 16;             // rows per grid sweep
  int i = blockIdx.x * 16 + pl;
  const f4 z = {0.f, 0.f, 0.f, 0.f};

  for (; i + 3 * rstride < n; i += 4 * rstride) {
    int ia = i, ib_ = i + rstride, ic = i + 2 * rstride, id = i + 3 * rstride;
    int ba = batch[ia], bbb = batch[ib_], bc = batch[ic], bd = batch[id];
    float sa = scores[ia], sb = scores[ib_], scs = scores[ic], sd = scores[id];
    u64 ka = ((u64)ordbits(sa) << 24) | (u32)ia;
    u64 kb = ((u64)ordbits(sb) << 24) | (u32)ib_;
    u64 kc = ((u64)ordbits(scs) << 24) | (u32)ic;
    u64 kd = ((u64)ordbits(sd) << 24) | (u32)id;
    size_t oa = (size_t)ia * 16 + ch, ob_ = (size_t)ib_ * 16 + ch;
    size_t oc = (size_t)ic * 16 + ch, od = (size_t)id * 16 + ch;
    f4 va = z, vb = z, vc = z, vd = z;
    if (ka >= ws->keysel[ba])  va = feats4[oa];
    if (kb >= ws->keysel[bbb]) vb = feats4[ob_];
    if (kc >= ws->keysel[bc])  vc = feats4[oc];
    if (kd >= ws->keysel[bd])  vd = feats4[od];
    out4[oa] = va;
    out4[ob_] = vb;
    out4[oc] = vc;
    out4[od] = vd;
  }
  for (; i < n; i += rstride) {
    int b = batch[i];
    u64 key = ((u64)ordbits(scores[i]) << 24) | (u32)i;
    size_t off = (size_t)i * 16 + (size_t)ch;
    f4 v = z;
    if (key >= ws->keysel[b]) v = feats4[off];
    out4[off] = v;
  }
}

// ---------------- fallback chain (tiny ws): exact, global-idx keys ----------------

__global__ void k_zero_hdr(WsHdr* ws) {
  int t = threadIdx.x;
  if (t < NBATCH) ws->counts[t] = 0;
}

__global__ void k_hist_fb(const int* __restrict__ batch, int n, WsHdr* ws) {
  __shared__ int h[NBATCH];
  if (threadIdx.x < NBATCH) h[threadIdx.x] = 0;
  __syncthreads();
  int stride = gridDim.x * blockDim.x;
  for (int i = blockIdx.x * blockDim.x + threadIdx.x; i < n; i += stride)
    atomicAdd(&h[batch[i]], 1);
  __syncthreads();
  if (threadIdx.x < NBATCH) atomicAdd(&ws->counts[threadIdx.x], h[threadIdx.x]);
}

__global__ void k_select_fb(const float* __restrict__ scores, WsHdr* ws) {
  __shared__ u32 hist[256];
  __shared__ u64 sh_prefix;
  __shared__ int sh_krem, sh_start;
  int b = blockIdx.x, t = threadIdx.x;
  if (t == 0) {
    int acc = 0; for (int x = 0; x < b; ++x) acc += ws->counts[x];
    sh_start = acc; sh_prefix = 0ull; sh_krem = ws->counts[b] >> 1;
  }
  __syncthreads();
  int start = sh_start, cnt = ws->counts[b];
  if (cnt == 0) { if (t == 0) ws->keysel[b] = 0ull; return; }
  for (int shift = 48; shift >= 0; shift -= 8) {
    for (int j = t; j < 256; j += blockDim.x) hist[j] = 0;
    __syncthreads();
    u64 prefix = sh_prefix;
    for (int idx = t; idx < cnt; idx += blockDim.x) {
      u64 key = ((u64)ordbits(scores[start + idx]) << 24) | (u32)(start + idx);
      if ((key >> (shift + 8)) == prefix)
        atomicAdd(&hist[(u32)(key >> shift) & 255u], 1u);
    }
    __syncthreads();
    if (t == 0) {
      int krem = sh_krem;
      u32 cum = 0, sel = 255;
      for (int j = 0; j < 256; ++j) {
        u32 c = hist[j];
        if ((u32)krem < cum + c) { sel = (u32)j; krem -= (int)cum; break; }
        cum += c;
      }
      sh_prefix = (sh_prefix << 8) | sel;
      sh_krem = krem;
    }
    __syncthreads();
  }
  if (t == 0) ws->keysel[b] = sh_prefix;
}

extern "C" void kernel_launch(void* const* d_in, const int* in_sizes, int n_in,
                              void* d_out, int out_size, void* d_ws, size_t ws_size,
                              hipStream_t stream) {
  const float* feats  = (const float*)d_in[0];
  const int*   batch  = (const int*)d_in[1];
  const float* scores = (const float*)d_in[2];
  float* out = (float*)d_out;
  int n = in_sizes[1];
  WsHdr* ws = (WsHdr*)d_ws;

  int nblk = (n + BPTS - 1) / BPTS;
  const size_t meta_bytes = (size_t)nblk * MSTRIDE * sizeof(u32);
  const size_t cand_bytes = (size_t)nblk * CAP_BLK * sizeof(u64);
  const size_t need = sizeof(WsHdr) + meta_bytes + cand_bytes;

  if (ws_size >= need) {
    u32* meta = (u32*)((char*)d_ws + sizeof(WsHdr));
    u64* cand = (u64*)((char*)d_ws + sizeof(WsHdr) + meta_bytes);
    k_pass1<<<nblk, 256, 0, stream>>>(batch, scores, n, meta, cand);
    k_final<<<NBATCH, 256, 0, stream>>>(scores, meta, nblk, cand, ws);
  } else {
    k_zero_hdr <<<1, 64, 0, stream>>>(ws);
    k_hist_fb  <<<1024, 256, 0, stream>>>(batch, n, ws);
    k_select_fb<<<NBATCH, 256, 0, stream>>>(scores, ws);
  }

  int blocks = (n + 15) / 16;
  if (blocks > APPLY_BLOCKS) blocks = APPLY_BLOCKS;   // grid-stride the rest
  k_apply<<<blocks, 256, 0, stream>>>((const f4*)feats, batch, scores, ws,
                                      (f4*)out, n);
}

// Round 18
// 122.220 us; speedup vs baseline: 1.1445x; 1.1445x over previous
//
#include <hip/hip_runtime.h>
#include <stdint.h>

#define NBATCH 32
#define VPT    4
#define BPTS   1024            // points per pass1 block (256*VPT)
#define BPTS_SHIFT 10
#define CAP_BLK 256            // candidate slots per block (expected ~82)
#define MSTRIDE 72             // u32s per block meta row: cnt[32] clo[32] candcnt pad[7]
#define CAPTOT 6144            // LDS gather capacity (expected ~2500/segment)
#define CAP2   512             // sub-bucket capacity in rank select
#define APPLY_BLOCKS 2048      // grid-stride apply (G11)

typedef unsigned long long u64;
typedef unsigned int u32;
typedef float f4 __attribute__((ext_vector_type(4)));

struct WsHdr {
  u64 keysel[NBATCH];   // k-th smallest 56-bit key per segment (b-byte masked off)
  int counts[NBATCH];   // fallback path only
};
// ws: WsHdr | u32 meta[nblk*MSTRIDE] | u64 cand[nblk*CAP_BLK]
// Nothing pre-zeroed: every meta row is fully written by its owning block;
// cand slots are only read up to the stored (clamped) count.

__device__ __forceinline__ u32 ordbits(float s) {
  u32 u = __float_as_uint(s);
  return (u & 0x80000000u) ? ~u : (u | 0x80000000u);
}
__device__ __forceinline__ u32 obL() { return ordbits(0.46f); }
__device__ __forceinline__ u32 obR() { return ordbits(0.54f); }

// ---------------- fast path (3 kernels, no zeroing, no global atomics) ------------

__global__ void k_pass1(const int* __restrict__ batch, const float* __restrict__ scores,
                        int n, u32* __restrict__ meta, u64* __restrict__ cand) {
  __shared__ int hc[NBATCH], hl[NBATCH];
  __shared__ int sc[256];
  int t = threadIdx.x, blk = blockIdx.x;
  if (t < NBATCH) { hc[t] = 0; hl[t] = 0; }
  __syncthreads();

  u64 wk[VPT]; int wcnt = 0;
  int i0 = blk * BPTS + t * VPT;
  #pragma unroll
  for (int v = 0; v < VPT; ++v) {
    int i = i0 + v;
    if (i < n) {
      int b = batch[i];
      u32 ob = ordbits(scores[i]);
      bool lo = ob < obL();
      u64 act = __ballot(1);
      int lead = (int)__ffsll((long long)act) - 1;
      int b0 = __shfl(b, lead, 64);
      bool uni = (__ballot(b == b0) == act);
      if (uni) {
        u64 lom = __ballot(lo);
        if ((t & 63) == lead) {
          atomicAdd(&hc[b0], (int)__popcll(act));
          if (lom) atomicAdd(&hl[b0], (int)__popcll(lom));
        }
      } else {
        atomicAdd(&hc[b], 1);
        if (lo) atomicAdd(&hl[b], 1);
      }
      if (!lo && ob < obR())
        wk[wcnt++] = ((u64)(u32)b << 56) | ((u64)ob << 24) | (u32)i;
    }
  }
  // block-wide compaction of window candidates (LDS scan, deterministic)
  sc[t] = wcnt; __syncthreads();
  for (int off = 1; off < 256; off <<= 1) {
    int v = (t >= off) ? sc[t - off] : 0;
    __syncthreads(); sc[t] += v; __syncthreads();
  }
  int excl = sc[t] - wcnt;
  int m = sc[255];
  u64* dst = cand + (size_t)blk * CAP_BLK;
  for (int j = 0; j < wcnt; ++j)
    if (excl + j < CAP_BLK) dst[excl + j] = wk[j];
  __syncthreads();
  u32* mrow = meta + (size_t)blk * MSTRIDE;
  if (t < NBATCH) { mrow[t] = (u32)hc[t]; mrow[NBATCH + t] = (u32)hl[t]; }
  if (t == 0) mrow[64] = (u32)m;              // true count (may exceed CAP_BLK)
}

// k_final: r13 form (coalesced meta reduce + range-limited gather)
__global__ void k_final(const float* __restrict__ scores, const u32* __restrict__ meta,
                        int nblk, const u64* __restrict__ cand, WsHdr* ws) {
  __shared__ u64 ck[CAPTOT];     // 48KB
  __shared__ u64 ck2[CAP2];      // 4KB
  __shared__ int sc[256];
  __shared__ int cw[NBATCH], clw[NBATCH], stw[NBATCH];
  __shared__ int sh_w, sh_krem, sh_m, sh_m2, sh_bad;
  int b = blockIdx.x, t = threadIdx.x;

  // Phase A: coalesced reduce of all 32 segment counts + clo + overflow flag.
  {
    int seg = t & 31, grp = t >> 5;
    int c = 0, l = 0, bd = 0;
    for (int blk = grp; blk < nblk; blk += 8) {
      const u32* mrow = meta + (size_t)blk * MSTRIDE;
      c += (int)mrow[seg];
      l += (int)mrow[NBATCH + seg];
      if (seg == 0) bd |= (mrow[64] > CAP_BLK);
    }
    sc[t] = c; __syncthreads();
    if (t < NBATCH) { int tot = 0; for (int g = 0; g < 8; ++g) tot += sc[g * 32 + t]; cw[t] = tot; }
    __syncthreads();
    sc[t] = l; __syncthreads();
    if (t < NBATCH) { int tot = 0; for (int g = 0; g < 8; ++g) tot += sc[g * 32 + t]; clw[t] = tot; }
    __syncthreads();
    sc[t] = bd; __syncthreads();
    if (t == 0) {
      int anyb = 0; for (int g = 0; g < 8; ++g) anyb |= sc[g * 32];
      sh_bad = anyb; sh_m = 0; sh_m2 = 0;
      int acc = 0;
      for (int x = 0; x < NBATCH; ++x) { stw[x] = acc; acc += cw[x]; }
    }
    __syncthreads();
  }
  int cnt = cw[b];
  if (cnt == 0) { if (t == 0) ws->keysel[b] = 0ull; return; }
  int krem = cnt >> 1;                        // ndrop = floor(cnt*0.5) exact
  int start = stw[b];

  // Phase B: gather candidates from ONLY this segment's block range (~32 blocks)
  {
    int blk0 = start >> BPTS_SHIFT;
    int blk1 = (start + cnt - 1) >> BPTS_SHIFT;
    int wave = t >> 6, lane = t & 63;
    for (int blk = blk0 + wave; blk <= blk1; blk += 4) {
      int cc = (int)meta[(size_t)blk * MSTRIDE + 64]; if (cc > CAP_BLK) cc = CAP_BLK;
      const u64* src = cand + (size_t)blk * CAP_BLK;
      for (int j = lane; j < cc; j += 64) {
        u64 s = src[j];
        if ((int)(s >> 56) == b) {
          int p = atomicAdd(&sh_m, 1);
          if (p < CAPTOT) ck[p] = s;
        }
      }
    }
  }
  __syncthreads();
  int m = sh_m;
  int krem2 = krem - clw[b];
  bool fast = !sh_bad && m <= CAPTOT && krem2 >= 0 && krem2 < m;

  if (fast) {
    const u32 span = obR() - obL();
    sc[t] = 0; __syncthreads();
    for (int j = t; j < m; j += 256) {
      u32 ob = (u32)(ck[j] >> 24);
      u32 bk = (u32)(((u64)(ob - obL()) << 8) / span);
      atomicAdd(&sc[bk], 1);
    }
    __syncthreads();
    int own = sc[t];
    for (int off = 1; off < 256; off <<= 1) {     // Hillis-Steele inclusive scan
      int v = (t >= off) ? sc[t - off] : 0;
      __syncthreads(); sc[t] += v; __syncthreads();
    }
    int excl = sc[t] - own;
    if (krem2 >= excl && krem2 < excl + own) { sh_w = t; sh_krem = krem2 - excl; }
    __syncthreads();
    int W = sh_w, krem3 = sh_krem;
    for (int j = t; j < m; j += 256) {            // compact winning bucket
      u32 ob = (u32)(ck[j] >> 24);
      u32 bk = (u32)(((u64)(ob - obL()) << 8) / span);
      if ((int)bk == W) {
        int p = atomicAdd(&sh_m2, 1);
        if (p < CAP2) ck2[p] = ck[j];
      }
    }
    __syncthreads();
    int m2 = sh_m2;
    if (m2 <= CAP2) {
      for (int j = t; j < m2; j += 256) {
        u64 key = ck2[j];
        int r = 0;
        for (int q = 0; q < m2; ++q) r += (ck2[q] < key);   // keys distinct
        if (r == krem3) ws->keysel[b] = key & 0x00FFFFFFFFFFFFFFull;  // strip b byte
      }
      return;
    }
    __syncthreads();   // sub-bucket overflow -> exact radix below
  }

  // exact in-block 8-bit radix select over segment [start, start+cnt)
  u64 prefix = 0; int kr = krem;
  for (int shift = 48; shift >= 0; shift -= 8) {
    sc[t] = 0;
    __syncthreads();
    for (int idx = t; idx < cnt; idx += 256) {
      u64 key = ((u64)ordbits(scores[start + idx]) << 24) | (u32)(start + idx);
      if ((key >> (shift + 8)) == prefix) atomicAdd(&sc[(int)((key >> shift) & 255)], 1);
    }
    __syncthreads();
    int own = sc[t];
    for (int off = 1; off < 256; off <<= 1) {
      int v = (t >= off) ? sc[t - off] : 0;
      __syncthreads(); sc[t] += v; __syncthreads();
    }
    int excl = sc[t] - own;
    if (kr >= excl && kr < excl + own) { sh_w = t; sh_krem = kr - excl; }
    __syncthreads();
    prefix = (prefix << 8) | (u32)sh_w;
    kr = sh_krem;
    __syncthreads();
  }
  if (t == 0) ws->keysel[b] = prefix;
}

// ---------------- apply: r16 measured-best (nt loads + plain stores, unroll x4) ---
__global__ void k_apply(const f4* __restrict__ feats4,
                        const int* __restrict__ batch,
                        const float* __restrict__ scores,
                        const WsHdr* __restrict__ ws,
                        f4* __restrict__ out4, int n) {
  int t = threadIdx.x;
  int pl = t >> 4, ch = t & 15;
  int rstride = gridDim.x * 16;             // rows per grid sweep
  int i = blockIdx.x * 16 + pl;
  const f4 z = {0.f, 0.f, 0.f, 0.f};

  for (; i + 3 * rstride < n; i += 4 * rstride) {
    int ia = i, ib_ = i + rstride, ic = i + 2 * rstride, id = i + 3 * rstride;
    int ba = batch[ia], bbb = batch[ib_], bc = batch[ic], bd = batch[id];
    float sa = scores[ia], sb = scores[ib_], scs = scores[ic], sd = scores[id];
    u64 ka = ((u64)ordbits(sa) << 24) | (u32)ia;
    u64 kb = ((u64)ordbits(sb) << 24) | (u32)ib_;
    u64 kc = ((u64)ordbits(scs) << 24) | (u32)ic;
    u64 kd = ((u64)ordbits(sd) << 24) | (u32)id;
    size_t oa = (size_t)ia * 16 + ch, ob_ = (size_t)ib_ * 16 + ch;
    size_t oc = (size_t)ic * 16 + ch, od = (size_t)id * 16 + ch;
    f4 va = z, vb = z, vc = z, vd = z;
    if (ka >= ws->keysel[ba])  va = __builtin_nontemporal_load(feats4 + oa);
    if (kb >= ws->keysel[bbb]) vb = __builtin_nontemporal_load(feats4 + ob_);
    if (kc >= ws->keysel[bc])  vc = __builtin_nontemporal_load(feats4 + oc);
    if (kd >= ws->keysel[bd])  vd = __builtin_nontemporal_load(feats4 + od);
    out4[oa] = va;
    out4[ob_] = vb;
    out4[oc] = vc;
    out4[od] = vd;
  }
  for (; i < n; i += rstride) {
    int b = batch[i];
    u64 key = ((u64)ordbits(scores[i]) << 24) | (u32)i;
    size_t off = (size_t)i * 16 + (size_t)ch;
    f4 v = z;
    if (key >= ws->keysel[b]) v = __builtin_nontemporal_load(feats4 + off);
    out4[off] = v;
  }
}

// ---------------- fallback chain (tiny ws): exact, global-idx keys ----------------

__global__ void k_zero_hdr(WsHdr* ws) {
  int t = threadIdx.x;
  if (t < NBATCH) ws->counts[t] = 0;
}

__global__ void k_hist_fb(const int* __restrict__ batch, int n, WsHdr* ws) {
  __shared__ int h[NBATCH];
  if (threadIdx.x < NBATCH) h[threadIdx.x] = 0;
  __syncthreads();
  int stride = gridDim.x * blockDim.x;
  for (int i = blockIdx.x * blockDim.x + threadIdx.x; i < n; i += stride)
    atomicAdd(&h[batch[i]], 1);
  __syncthreads();
  if (threadIdx.x < NBATCH) atomicAdd(&ws->counts[threadIdx.x], h[threadIdx.x]);
}

__global__ void k_select_fb(const float* __restrict__ scores, WsHdr* ws) {
  __shared__ u32 hist[256];
  __shared__ u64 sh_prefix;
  __shared__ int sh_krem, sh_start;
  int b = blockIdx.x, t = threadIdx.x;
  if (t == 0) {
    int acc = 0; for (int x = 0; x < b; ++x) acc += ws->counts[x];
    sh_start = acc; sh_prefix = 0ull; sh_krem = ws->counts[b] >> 1;
  }
  __syncthreads();
  int start = sh_start, cnt = ws->counts[b];
  if (cnt == 0) { if (t == 0) ws->keysel[b] = 0ull; return; }
  for (int shift = 48; shift >= 0; shift -= 8) {
    for (int j = t; j < 256; j += blockDim.x) hist[j] = 0;
    __syncthreads();
    u64 prefix = sh_prefix;
    for (int idx = t; idx < cnt; idx += blockDim.x) {
      u64 key = ((u64)ordbits(scores[start + idx]) << 24) | (u32)(start + idx);
      if ((key >> (shift + 8)) == prefix)
        atomicAdd(&hist[(u32)(key >> shift) & 255u], 1u);
    }
    __syncthreads();
    if (t == 0) {
      int krem = sh_krem;
      u32 cum = 0, sel = 255;
      for (int j = 0; j < 256; ++j) {
        u32 c = hist[j];
        if ((u32)krem < cum + c) { sel = (u32)j; krem -= (int)cum; break; }
        cum += c;
      }
      sh_prefix = (sh_prefix << 8) | sel;
      sh_krem = krem;
    }
    __syncthreads();
  }
  if (t == 0) ws->keysel[b] = sh_prefix;
}

extern "C" void kernel_launch(void* const* d_in, const int* in_sizes, int n_in,
                              void* d_out, int out_size, void* d_ws, size_t ws_size,
                              hipStream_t stream) {
  const float* feats  = (const float*)d_in[0];
  const int*   batch  = (const int*)d_in[1];
  const float* scores = (const float*)d_in[2];
  float* out = (float*)d_out;
  int n = in_sizes[1];
  WsHdr* ws = (WsHdr*)d_ws;

  int nblk = (n + BPTS - 1) / BPTS;
  const size_t meta_bytes = (size_t)nblk * MSTRIDE * sizeof(u32);
  const size_t cand_bytes = (size_t)nblk * CAP_BLK * sizeof(u64);
  const size_t need = sizeof(WsHdr) + meta_bytes + cand_bytes;

  if (ws_size >= need) {
    u32* meta = (u32*)((char*)d_ws + sizeof(WsHdr));
    u64* cand = (u64*)((char*)d_ws + sizeof(WsHdr) + meta_bytes);
    k_pass1<<<nblk, 256, 0, stream>>>(batch, scores, n, meta, cand);
    k_final<<<NBATCH, 256, 0, stream>>>(scores, meta, nblk, cand, ws);
  } else {
    k_zero_hdr <<<1, 64, 0, stream>>>(ws);
    k_hist_fb  <<<1024, 256, 0, stream>>>(batch, n, ws);
    k_select_fb<<<NBATCH, 256, 0, stream>>>(scores, ws);
  }

  int blocks = (n + 15) / 16;
  if (blocks > APPLY_BLOCKS) blocks = APPLY_BLOCKS;   // grid-stride the rest
  k_apply<<<blocks, 256, 0, stream>>>((const f4*)feats, batch, scores, ws,
                                      (f4*)out, n);
}